// Round 1
// baseline (442.017 us; speedup 1.0000x reference)
//
#include <hip/hip_runtime.h>
#include <math.h>

#define DIM 128
#define BM 128
#define PADA 68          // 64-wide A chunk + 4 pad (keeps b64 reads conflict-free, 16B-aligned rows)
#define R1_CHUNK 4096

// ---------------- Phase 0: exclusive scan of lengths -> offsets ----------------
__global__ __launch_bounds__(1024) void scan_kernel(const int* __restrict__ lengths,
                                                    int* __restrict__ offsets, int batch) {
    __shared__ int tsum[1024];
    int tid = threadIdx.x;
    int per = (batch + 1023) >> 10;
    int start = tid * per;
    int s = 0;
    for (int i = 0; i < per; ++i) {
        int idx = start + i;
        if (idx < batch) s += lengths[idx];
    }
    tsum[tid] = s;
    __syncthreads();
    for (int off = 1; off < 1024; off <<= 1) {
        int v = (tid >= off) ? tsum[tid - off] : 0;
        __syncthreads();
        tsum[tid] += v;
        __syncthreads();
    }
    int base = (tid == 0) ? 0 : tsum[tid - 1];
    for (int i = 0; i < per; ++i) {
        int idx = start + i;
        if (idx < batch) { offsets[idx] = base; base += lengths[idx]; }
    }
}

// ---------------- Phase 1: scores = relu(emb @ W1 + b1) @ W2 + b2 ----------------
// 128-row tile per block, K chunked by 64. LDS: A-chunk 34816B + W1-chunk 32768B + 1KB
// => 68.6KB -> 2 blocks/CU (4 waves/SIMD). Thread (tx,ty): 4 rows x 8 cols register tile.
__global__ __launch_bounds__(512, 4) void score_kernel(
        const float* __restrict__ emb, const float* __restrict__ W1,
        const float* __restrict__ b1, const float* __restrict__ W2,
        const float* __restrict__ b2, float* __restrict__ scores, int T) {
    __shared__ float sA[BM][PADA];
    __shared__ float sW1c[64 * DIM];
    __shared__ float sb1[DIM];
    __shared__ float sW2[DIM];

    int tid = threadIdx.x;
    if (tid < DIM) { sb1[tid] = b1[tid]; sW2[tid] = W2[tid]; }
    long row0 = (long)blockIdx.x * BM;
    int tx = tid & 15, ty = tid >> 4;

    float acc[4][8];
    #pragma unroll
    for (int i = 0; i < 4; ++i)
        #pragma unroll
        for (int j = 0; j < 8; ++j) acc[i][j] = 0.0f;

    for (int kk = 0; kk < DIM; kk += 64) {
        __syncthreads();
        // stage A chunk: 128 rows x 64 k (float4 coalesced, b128 LDS writes, 16B aligned)
        #pragma unroll
        for (int i = 0; i < 4; ++i) {
            int f = tid + i * 512;      // 0..2047 float4s
            int r = f >> 4;             // 0..127
            int k4 = f & 15;            // 0..15
            long row = row0 + r;
            float4 v = make_float4(0.f, 0.f, 0.f, 0.f);
            if (row < T) v = ((const float4*)emb)[row * 32 + (kk >> 2) + k4];
            *(float4*)&sA[r][k4 * 4] = v;
        }
        // stage W1 chunk: rows kk..kk+63, all 128 cols
        #pragma unroll
        for (int i = 0; i < 4; ++i) {
            int f = tid + i * 512;
            ((float4*)sW1c)[f] = ((const float4*)W1)[kk * 32 + f];
        }
        __syncthreads();

        #pragma unroll 2
        for (int k2 = 0; k2 < 64; k2 += 2) {
            float2 a[4];
            #pragma unroll
            for (int i = 0; i < 4; ++i)
                a[i] = *(const float2*)&sA[ty * 4 + i][k2];   // broadcast reads, 2 banks
            const float* Bp = &sW1c[k2 * DIM + tx * 8];
            float b0[8], b1r[8];
            *(float4*)&b0[0]  = *(const float4*)(Bp);
            *(float4*)&b0[4]  = *(const float4*)(Bp + 4);
            *(float4*)&b1r[0] = *(const float4*)(Bp + DIM);
            *(float4*)&b1r[4] = *(const float4*)(Bp + DIM + 4);
            #pragma unroll
            for (int i = 0; i < 4; ++i) {
                #pragma unroll
                for (int j = 0; j < 8; ++j) {
                    acc[i][j] = fmaf(a[i].x, b0[j],  acc[i][j]);
                    acc[i][j] = fmaf(a[i].y, b1r[j], acc[i][j]);
                }
            }
        }
    }

    // epilogue: + b1, relu, dot W2 (this thread's 8 cols), reduce over the 16 tx lanes
    float p[4];
    #pragma unroll
    for (int i = 0; i < 4; ++i) {
        float s = 0.f;
        #pragma unroll
        for (int j = 0; j < 8; ++j) {
            float h = acc[i][j] + sb1[tx * 8 + j];
            h = fmaxf(h, 0.f);
            s = fmaf(h, sW2[tx * 8 + j], s);
        }
        p[i] = s;
    }
    #pragma unroll
    for (int m = 1; m < 16; m <<= 1) {
        #pragma unroll
        for (int i = 0; i < 4; ++i) p[i] += __shfl_xor(p[i], m, 64);
    }
    if (tx == 0) {
        float bb = b2[0];
        #pragma unroll
        for (int i = 0; i < 4; ++i) {
            long r = row0 + ty * 4 + i;
            if (r < T) scores[r] = p[i] + bb;
        }
    }
}

// ---------------- Phase 2a: per-chunk max and sum(exp(s - localmax)) ----------------
__global__ __launch_bounds__(256) void reduce1_kernel(const float* __restrict__ scores, int T,
        float* __restrict__ partmax, float* __restrict__ partsum) {
    int tid = threadIdx.x;
    long start = (long)blockIdx.x * R1_CHUNK;
    float v[16];
    float m = -INFINITY;
    #pragma unroll
    for (int i = 0; i < 16; ++i) {
        long idx = start + tid + i * 256;
        v[i] = (idx < T) ? scores[idx] : -INFINITY;
        m = fmaxf(m, v[i]);
    }
    #pragma unroll
    for (int off = 32; off >= 1; off >>= 1) m = fmaxf(m, __shfl_xor(m, off, 64));
    __shared__ float redm[4], reds[4];
    int wave = tid >> 6, lane = tid & 63;
    if (lane == 0) redm[wave] = m;
    __syncthreads();
    float M = fmaxf(fmaxf(redm[0], redm[1]), fmaxf(redm[2], redm[3]));
    float s = 0.f;
    #pragma unroll
    for (int i = 0; i < 16; ++i) s += expf(v[i] - M);   // exp(-inf)=0 handles tails
    #pragma unroll
    for (int off = 32; off >= 1; off >>= 1) s += __shfl_xor(s, off, 64);
    if (lane == 0) reds[wave] = s;
    __syncthreads();
    if (tid == 0) {
        partmax[blockIdx.x] = M;
        partsum[blockIdx.x] = reds[0] + reds[1] + reds[2] + reds[3];
    }
}

// ---------------- Phase 2b: combine partials -> global M, 1/S ----------------
__global__ __launch_bounds__(256) void reduce2_kernel(const float* __restrict__ partmax,
        const float* __restrict__ partsum, int nb, float* __restrict__ stats) {
    int tid = threadIdx.x;
    float m = -INFINITY;
    for (int i = tid; i < nb; i += 256) m = fmaxf(m, partmax[i]);
    #pragma unroll
    for (int off = 32; off >= 1; off >>= 1) m = fmaxf(m, __shfl_xor(m, off, 64));
    __shared__ float redm[4], reds[4];
    int wave = tid >> 6, lane = tid & 63;
    if (lane == 0) redm[wave] = m;
    __syncthreads();
    float M = fmaxf(fmaxf(redm[0], redm[1]), fmaxf(redm[2], redm[3]));
    float s = 0.f;
    for (int i = tid; i < nb; i += 256) s += partsum[i] * expf(partmax[i] - M);
    #pragma unroll
    for (int off = 32; off >= 1; off >>= 1) s += __shfl_xor(s, off, 64);
    if (lane == 0) reds[wave] = s;
    __syncthreads();
    if (tid == 0) {
        float S = reds[0] + reds[1] + reds[2] + reds[3];
        stats[0] = M;
        stats[1] = 1.0f / S;
    }
}

// ---------------- Phase 3: pooled[b][d] = sum_j w_j * emb[off+j][d] ----------------
__global__ __launch_bounds__(128) void pool_kernel(const float* __restrict__ emb,
        const float* __restrict__ scores, const int* __restrict__ offsets,
        const int* __restrict__ lengths, const float* __restrict__ stats,
        float* __restrict__ out) {
    int b = blockIdx.x;
    int off = offsets[b];
    int len = lengths[b];
    float M = stats[0], invS = stats[1];
    int tid = threadIdx.x;
    __shared__ float sw[128];
    float acc = 0.f;
    for (int base = 0; base < len; base += 128) {
        int n = min(128, len - base);
        __syncthreads();
        if (tid < n) sw[tid] = expf(scores[off + base + tid] - M) * invS;
        __syncthreads();
        for (int j = 0; j < n; ++j)
            acc = fmaf(sw[j], emb[(long)(off + base + j) * DIM + tid], acc);
    }
    out[(long)b * DIM + tid] = acc;
}

extern "C" void kernel_launch(void* const* d_in, const int* in_sizes, int n_in,
                              void* d_out, int out_size, void* d_ws, size_t ws_size,
                              hipStream_t stream) {
    const float* emb     = (const float*)d_in[0];
    const float* W1      = (const float*)d_in[1];
    const float* b1      = (const float*)d_in[2];
    const float* W2      = (const float*)d_in[3];
    const float* b2      = (const float*)d_in[4];
    const int*   lengths = (const int*)d_in[5];
    int T = in_sizes[0] / DIM;
    int batch = in_sizes[5];
    float* out = (float*)d_out;

    // ws layout: scores[T] | offsets[batch] | partmax[nb1] | partsum[nb1] | stats[2]
    float* scores  = (float*)d_ws;
    int*   offsets = (int*)(scores + T);
    int nb1 = (T + R1_CHUNK - 1) / R1_CHUNK;
    float* partmax = (float*)(offsets + batch);
    float* partsum = partmax + nb1;
    float* stats   = partsum + nb1;

    scan_kernel<<<1, 1024, 0, stream>>>(lengths, offsets, batch);
    score_kernel<<<(T + BM - 1) / BM, 512, 0, stream>>>(emb, W1, b1, W2, b2, scores, T);
    reduce1_kernel<<<nb1, 256, 0, stream>>>(scores, T, partmax, partsum);
    reduce2_kernel<<<1, 256, 0, stream>>>(partmax, partsum, nb1, stats);
    pool_kernel<<<batch, DIM, 0, stream>>>(emb, scores, offsets, lengths, stats, out);
}

// Round 2
// 266.796 us; speedup vs baseline: 1.6568x; 1.6568x over previous
//
#include <hip/hip_runtime.h>
#include <math.h>

#define DIM 128
#define R1_CHUNK 4096

typedef __attribute__((ext_vector_type(8))) short bf16x8;
typedef __attribute__((ext_vector_type(4))) float f32x4;

// RNE float -> bf16 bits
static __device__ __forceinline__ ushort f2bf(float f) {
    unsigned u = __float_as_uint(f);
    u += 0x7FFFu + ((u >> 16) & 1u);
    return (ushort)(u >> 16);
}

// ---------------- Phase 0: exclusive scan of lengths -> offsets ----------------
__global__ __launch_bounds__(1024) void scan_kernel(const int* __restrict__ lengths,
                                                    int* __restrict__ offsets, int batch) {
    __shared__ int tsum[1024];
    int tid = threadIdx.x;
    int per = (batch + 1023) >> 10;
    int start = tid * per;
    int s = 0;
    for (int i = 0; i < per; ++i) {
        int idx = start + i;
        if (idx < batch) s += lengths[idx];
    }
    tsum[tid] = s;
    __syncthreads();
    for (int off = 1; off < 1024; off <<= 1) {
        int v = (tid >= off) ? tsum[tid - off] : 0;
        __syncthreads();
        tsum[tid] += v;
        __syncthreads();
    }
    int base = (tid == 0) ? 0 : tsum[tid - 1];
    for (int i = 0; i < per; ++i) {
        int idx = start + i;
        if (idx < batch) { offsets[idx] = base; base += lengths[idx]; }
    }
}

// ---------------- Phase 1: scores = relu(emb @ W1 + b1) @ W2 + b2  (bf16 MFMA) ----
// Persistent blocks (512 = 2/CU). W1^T staged once to LDS (bf16, chunk-XOR swizzle),
// all 32 B-frags kept in registers (128 VGPR). Per 128-row tile: stage emb fp32->bf16
// into LDS (swizzled), 64 MFMAs/wave (16x16x32), fused bias+relu+W2-dot epilogue.
// LDS frag reads: chunk pos = c ^ (row&7) -> 16 lanes at 256B row stride spread over
// 8 bank-quads (2-way = free) instead of 16-way conflict.
__global__ __launch_bounds__(256, 2) void score_kernel(
        const float* __restrict__ emb, const float* __restrict__ W1,
        const float* __restrict__ b1, const float* __restrict__ W2,
        const float* __restrict__ b2, float* __restrict__ scores, int T) {
    __shared__ ushort sA[128 * 128];   // bf16; holds W1^T during init, then A tiles

    int tid = threadIdx.x;
    int lane = tid & 63;
    int wv = tid >> 6;              // wave 0..3
    int lr = lane & 15;             // row/col within 16-tile
    int lg = lane >> 4;             // k-group 0..3

    // ---- stage W1^T (bf16, swizzled): row n, k. gather-read W1[k][n] (L2), b64 writes
    for (int i = 0; i < 16; ++i) {
        int q = tid + i * 256;          // 0..4095
        int n = q >> 5;                 // 0..127 (row of W1^T)
        int k4 = q & 31;                // group of 4 consecutive k
        ushort4 w;
        w.x = f2bf(W1[(k4 * 4 + 0) * DIM + n]);
        w.y = f2bf(W1[(k4 * 4 + 1) * DIM + n]);
        w.z = f2bf(W1[(k4 * 4 + 2) * DIM + n]);
        w.w = f2bf(W1[(k4 * 4 + 3) * DIM + n]);
        int c = k4 >> 1;                // 16B chunk index (8 bf16)
        int addr16 = n * 128 + ((c ^ (n & 7)) * 8) + (k4 & 1) * 4;
        *(ushort4*)&sA[addr16] = w;
    }
    __syncthreads();

    // ---- load all B-frags to registers: bfrag[ct][kc], lane holds W1T[n=ct*16+lr][k0..k0+7]
    bf16x8 bfrag[8][4];
    #pragma unroll
    for (int ct = 0; ct < 8; ++ct) {
        int n = ct * 16 + lr;
        #pragma unroll
        for (int kc = 0; kc < 4; ++kc) {
            int c = lg + kc * 4;
            int addr16 = n * 128 + ((c ^ (n & 7)) * 8);
            bfrag[ct][kc] = *(const bf16x8*)&sA[addr16];
        }
    }
    // per-thread epilogue constants for this lane's 8 columns
    float b1reg[8], w2reg[8];
    #pragma unroll
    for (int ct = 0; ct < 8; ++ct) {
        b1reg[ct] = b1[ct * 16 + lr];
        w2reg[ct] = W2[ct * 16 + lr];
    }
    float b2v = b2[0];
    __syncthreads();   // W1^T reads done; sA now reusable for A tiles

    int ntiles = (T + 127) >> 7;
    for (int tile = blockIdx.x; tile < ntiles; tile += gridDim.x) {
        // ---- stage A tile: 128 rows x 128 k, fp32 -> bf16, swizzled
        #pragma unroll
        for (int i = 0; i < 16; ++i) {
            int q = tid + i * 256;
            int r = q >> 5;
            int k4 = q & 31;
            long row = (long)tile * 128 + r;
            float4 v = make_float4(0.f, 0.f, 0.f, 0.f);
            if (row < T) v = ((const float4*)emb)[row * 32 + k4];
            ushort4 w;
            w.x = f2bf(v.x); w.y = f2bf(v.y); w.z = f2bf(v.z); w.w = f2bf(v.w);
            int c = k4 >> 1;
            int addr16 = r * 128 + ((c ^ (r & 7)) * 8) + (k4 & 1) * 4;
            *(ushort4*)&sA[addr16] = w;
        }
        __syncthreads();

        #pragma unroll
        for (int rt = 0; rt < 2; ++rt) {
            int r = wv * 32 + rt * 16 + lr;       // local row in tile
            bf16x8 a[4];
            #pragma unroll
            for (int kc = 0; kc < 4; ++kc) {
                int c = lg + kc * 4;
                int addr16 = r * 128 + ((c ^ (r & 7)) * 8);
                a[kc] = *(const bf16x8*)&sA[addr16];
            }
            f32x4 acc[8];
            #pragma unroll
            for (int ct = 0; ct < 8; ++ct) acc[ct] = (f32x4)(0.f);
            #pragma unroll
            for (int ct = 0; ct < 8; ++ct)
                #pragma unroll
                for (int kc = 0; kc < 4; ++kc)
                    acc[ct] = __builtin_amdgcn_mfma_f32_16x16x32_bf16(a[kc], bfrag[ct][kc], acc[ct], 0, 0, 0);

            // epilogue: h = relu(acc + b1), partial = h . W2 over this lane's 8 cols,
            // reduce over the 16 lanes of the col dimension, write 4 rows per k-group.
            #pragma unroll
            for (int reg = 0; reg < 4; ++reg) {
                float s = 0.f;
                #pragma unroll
                for (int ct = 0; ct < 8; ++ct) {
                    float h = acc[ct][reg] + b1reg[ct];
                    h = fmaxf(h, 0.f);
                    s = fmaf(h, w2reg[ct], s);
                }
                s += __shfl_xor(s, 1, 64);
                s += __shfl_xor(s, 2, 64);
                s += __shfl_xor(s, 4, 64);
                s += __shfl_xor(s, 8, 64);
                if (lr == 0) {
                    long grow = (long)tile * 128 + wv * 32 + rt * 16 + lg * 4 + reg;
                    if (grow < T) scores[grow] = s + b2v;
                }
            }
        }
        __syncthreads();
    }
}

// ---------------- Phase 2a: per-chunk max and sum(exp(s - localmax)) ----------------
__global__ __launch_bounds__(256) void reduce1_kernel(const float* __restrict__ scores, int T,
        float* __restrict__ partmax, float* __restrict__ partsum) {
    int tid = threadIdx.x;
    long start = (long)blockIdx.x * R1_CHUNK;
    float v[16];
    float m = -INFINITY;
    #pragma unroll
    for (int i = 0; i < 16; ++i) {
        long idx = start + tid + i * 256;
        v[i] = (idx < T) ? scores[idx] : -INFINITY;
        m = fmaxf(m, v[i]);
    }
    #pragma unroll
    for (int off = 32; off >= 1; off >>= 1) m = fmaxf(m, __shfl_xor(m, off, 64));
    __shared__ float redm[4], reds[4];
    int wave = tid >> 6, lane = tid & 63;
    if (lane == 0) redm[wave] = m;
    __syncthreads();
    float M = fmaxf(fmaxf(redm[0], redm[1]), fmaxf(redm[2], redm[3]));
    float s = 0.f;
    #pragma unroll
    for (int i = 0; i < 16; ++i) s += expf(v[i] - M);
    #pragma unroll
    for (int off = 32; off >= 1; off >>= 1) s += __shfl_xor(s, off, 64);
    if (lane == 0) reds[wave] = s;
    __syncthreads();
    if (tid == 0) {
        partmax[blockIdx.x] = M;
        partsum[blockIdx.x] = reds[0] + reds[1] + reds[2] + reds[3];
    }
}

// ---------------- Phase 2b: combine partials -> global M, 1/S ----------------
__global__ __launch_bounds__(256) void reduce2_kernel(const float* __restrict__ partmax,
        const float* __restrict__ partsum, int nb, float* __restrict__ stats) {
    int tid = threadIdx.x;
    float m = -INFINITY;
    for (int i = tid; i < nb; i += 256) m = fmaxf(m, partmax[i]);
    #pragma unroll
    for (int off = 32; off >= 1; off >>= 1) m = fmaxf(m, __shfl_xor(m, off, 64));
    __shared__ float redm[4], reds[4];
    int wave = tid >> 6, lane = tid & 63;
    if (lane == 0) redm[wave] = m;
    __syncthreads();
    float M = fmaxf(fmaxf(redm[0], redm[1]), fmaxf(redm[2], redm[3]));
    float s = 0.f;
    for (int i = tid; i < nb; i += 256) s += partsum[i] * expf(partmax[i] - M);
    #pragma unroll
    for (int off = 32; off >= 1; off >>= 1) s += __shfl_xor(s, off, 64);
    if (lane == 0) reds[wave] = s;
    __syncthreads();
    if (tid == 0) {
        float S = reds[0] + reds[1] + reds[2] + reds[3];
        stats[0] = M;
        stats[1] = 1.0f / S;
    }
}

// ---------------- Phase 3: pooled[b][d] = sum_j w_j * emb[off+j][d] ----------------
__global__ __launch_bounds__(128) void pool_kernel(const float* __restrict__ emb,
        const float* __restrict__ scores, const int* __restrict__ offsets,
        const int* __restrict__ lengths, const float* __restrict__ stats,
        float* __restrict__ out) {
    int b = blockIdx.x;
    int off = offsets[b];
    int len = lengths[b];
    float M = stats[0], invS = stats[1];
    int tid = threadIdx.x;
    __shared__ float sw[128];
    float acc = 0.f;
    for (int base = 0; base < len; base += 128) {
        int n = min(128, len - base);
        __syncthreads();
        if (tid < n) sw[tid] = expf(scores[off + base + tid] - M) * invS;
        __syncthreads();
        for (int j = 0; j < n; ++j)
            acc = fmaf(sw[j], emb[(long)(off + base + j) * DIM + tid], acc);
    }
    out[(long)b * DIM + tid] = acc;
}

extern "C" void kernel_launch(void* const* d_in, const int* in_sizes, int n_in,
                              void* d_out, int out_size, void* d_ws, size_t ws_size,
                              hipStream_t stream) {
    const float* emb     = (const float*)d_in[0];
    const float* W1      = (const float*)d_in[1];
    const float* b1      = (const float*)d_in[2];
    const float* W2      = (const float*)d_in[3];
    const float* b2      = (const float*)d_in[4];
    const int*   lengths = (const int*)d_in[5];
    int T = in_sizes[0] / DIM;
    int batch = in_sizes[5];
    float* out = (float*)d_out;

    // ws layout: scores[T] | offsets[batch] | partmax[nb1] | partsum[nb1] | stats[2]
    float* scores  = (float*)d_ws;
    int*   offsets = (int*)(scores + T);
    int nb1 = (T + R1_CHUNK - 1) / R1_CHUNK;
    float* partmax = (float*)(offsets + batch);
    float* partsum = partmax + nb1;
    float* stats   = partsum + nb1;

    scan_kernel<<<1, 1024, 0, stream>>>(lengths, offsets, batch);
    score_kernel<<<512, 256, 0, stream>>>(emb, W1, b1, W2, b2, scores, T);
    reduce1_kernel<<<nb1, 256, 0, stream>>>(scores, T, partmax, partsum);
    reduce2_kernel<<<1, 256, 0, stream>>>(partmax, partsum, nb1, stats);
    pool_kernel<<<batch, DIM, 0, stream>>>(emb, scores, offsets, lengths, stats, out);
}